// Round 3
// baseline (330.079 us; speedup 1.0000x reference)
//
#include <hip/hip_runtime.h>

// image2patch / im2col gather, streaming ILP-4 + nontemporal stores:
//   input  : (32, 8, 256, 256) fp32 -> 256 images of 256x256
//   output : (256, 3969, 64) fp32; patch p: row0=4*(p/63), col0=4*(p%63)
//
// R1 (divergent gather) == R2 (LDS staged) == 298 us: reads are not the
// bottleneck. This version maximizes per-thread memory-level parallelism
// (4 independent load->store chains, no barrier) and uses nontemporal
// stores so the 260 MB output stream does not evict the 3.9x-reused input
// from L2.
//
// Each thread handles 4 output float4s at gid + j*G (G = total/4). Lanes
// within a wave are consecutive for every j -> every store is a fully
// coalesced 1 KB wave store; input addresses are 16B-aligned float4s.

constexpr unsigned NPDIM   = 63;            // patch positions per dim
constexpr unsigned PATCHES = NPDIM * NPDIM; // 3969
constexpr unsigned CHUNKS  = 16;            // float4 chunks per 8x8 patch
constexpr unsigned NIMG    = 256;           // 32*8 images
constexpr unsigned TOTAL4  = NIMG * PATCHES * CHUNKS; // 16,257,024
constexpr unsigned ILP     = 4;
constexpr unsigned G       = TOTAL4 / ILP;  // 4,064,256 = 15876 * 256

using fv4 = __attribute__((ext_vector_type(4))) float;

__global__ __launch_bounds__(256) void image2patch_kernel(
    const fv4* __restrict__ in4, fv4* __restrict__ out4) {
    unsigned gid = blockIdx.x * 256u + threadIdx.x;

    fv4 v[ILP];
    unsigned dst[ILP];
    #pragma unroll
    for (unsigned j = 0; j < ILP; ++j) {
        unsigned g  = gid + j * G;
        unsigned k4 = g & 15u;              // chunk within patch
        unsigned pn = g >> 4;               // n*3969 + p
        unsigned n  = pn / PATCHES;
        unsigned p  = pn - n * PATCHES;
        unsigned pr = p / NPDIM;
        unsigned pc = p - pr * NPDIM;
        unsigned row  = pr * 4u + (k4 >> 1);   // image row, 0..255
        unsigned col4 = pc + (k4 & 1u);        // image col / 4, 0..63
        v[j]   = in4[n * 16384u + row * 64u + col4];
        dst[j] = g;
    }
    #pragma unroll
    for (unsigned j = 0; j < ILP; ++j) {
        __builtin_nontemporal_store(v[j], &out4[dst[j]]);
    }
}

extern "C" void kernel_launch(void* const* d_in, const int* in_sizes, int n_in,
                              void* d_out, int out_size, void* d_ws, size_t ws_size,
                              hipStream_t stream) {
    const fv4* in4 = (const fv4*)d_in[0];
    fv4* out4 = (fv4*)d_out;
    unsigned blocks = G / 256u;   // 15876, exact
    image2patch_kernel<<<blocks, 256, 0, stream>>>(in4, out4);
}

// Round 4
// 316.141 us; speedup vs baseline: 1.0441x; 1.0441x over previous
//
#include <hip/hip_runtime.h>

// image2patch / im2col gather — persistent pipelined LDS version.
//   input  : (32, 8, 256, 256) fp32 -> 256 images of 256x256
//   output : (256, 3969, 64) fp32; patch p: row0=4*(p/63), col0=4*(p%63)
//
// Evidence so far: R1 (pure gather) == R2 (LDS, 1 band/block) == 298 us;
// R3 (nontemporal) = 330 us. Theory: per-block store-drain / launch churn.
// This version: 2016 blocks (7.875/CU, fully co-resident, 31.5 waves/CU),
// each streams 8 (n,pr) bands through a double-buffered LDS pipeline:
//   ds_write band i -> buf[i&1]; barrier; issue band i+1 global loads;
//   emit band i's 1008 coalesced float4 stores from LDS.
// One barrier per 16 KB of stores; next-band loads always in flight
// behind the store stream. Padded LDS rows (65 float4) kill bank conflicts.

constexpr unsigned NPDIM   = 63;             // patch positions per dim
constexpr unsigned PATCHES = NPDIM * NPDIM;  // 3969
constexpr unsigned CHUNKS  = 16;             // float4 chunks per 8x8 patch
constexpr unsigned ROWPAD  = 65;             // LDS row stride in float4s
constexpr unsigned BANDS   = 256u * NPDIM;   // 16128 (image, patch-row) pairs
constexpr unsigned BPB     = 8;              // bands per block
constexpr unsigned BLOCKS  = BANDS / BPB;    // 2016

__global__ __launch_bounds__(256, 8) void image2patch_kernel(
    const float4* __restrict__ in4, float4* __restrict__ out4) {
    __shared__ float4 lds[2][8 * ROWPAD];    // 2 x 8.3 KB

    unsigned t = threadIdx.x;
    unsigned band0 = blockIdx.x * BPB;

    // staging decomposition (elements t and t+256 of the 512-float4 band)
    unsigned r0 = t >> 6, c0 = t & 63u;
    unsigned i1 = t + 256u;
    unsigned r1 = i1 >> 6, c1 = i1 & 63u;

    // preload band 0
    unsigned n  = band0 / NPDIM;
    unsigned pr = band0 - n * NPDIM;
    unsigned inbase = n * 16384u + pr * 256u;   // image=16384 f4, row=64 f4
    float4 v0 = in4[inbase + t];
    float4 v1 = in4[inbase + 256u + t];

    for (unsigned i = 0; i < BPB; ++i) {
        unsigned buf = i & 1u;
        lds[buf][r0 * ROWPAD + c0] = v0;
        lds[buf][r1 * ROWPAD + c1] = v1;
        unsigned outbase = (n * PATCHES + pr * NPDIM) * CHUNKS;
        __syncthreads();

        // issue next band's global loads before the store phase
        if (i + 1 < BPB) {
            unsigned nb  = band0 + i + 1;
            unsigned nn  = nb / NPDIM;
            unsigned npr = nb - nn * NPDIM;
            unsigned nin = nn * 16384u + npr * 256u;
            v0 = in4[nin + t];
            v1 = in4[nin + 256u + t];
            n = nn; pr = npr;
        }

        // emit 63 patches = 1008 float4, fully coalesced
        #pragma unroll
        for (unsigned it = 0; it < 4; ++it) {
            unsigned idx = it * 256u + t;
            if (idx < NPDIM * CHUNKS) {              // 1008
                unsigned pc  = idx >> 4;
                unsigned k4  = idx & 15u;
                unsigned di  = k4 >> 1;
                unsigned dj4 = k4 & 1u;
                out4[outbase + idx] = lds[buf][di * ROWPAD + pc + dj4];
            }
        }
        // no trailing barrier: double buffer + next iteration's barrier
        // separate this buffer's reads from its next overwrite
    }
}

extern "C" void kernel_launch(void* const* d_in, const int* in_sizes, int n_in,
                              void* d_out, int out_size, void* d_ws, size_t ws_size,
                              hipStream_t stream) {
    const float4* in4 = (const float4*)d_in[0];
    float4* out4 = (float4*)d_out;
    image2patch_kernel<<<BLOCKS, 256, 0, stream>>>(in4, out4);
}

// Round 5
// 293.918 us; speedup vs baseline: 1.1230x; 1.0756x over previous
//
#include <hip/hip_runtime.h>

// image2patch / im2col gather, LDS-staged + NONTEMPORAL output stores.
// Identical to R2 (best: 298.2 us) except the output store bypasses cache
// allocation. Theory: the harness's 1.016 GB 0xAA poison fill leaves L3
// full of dirty lines; cached output stores evict ~254 MB of poison to HBM
// inside our kernel's window (+44 us). NT stores leave the poison in L3
// (overwritten in-place by the next fill) and stream output straight out.
//
//   input  : (32, 8, 256, 256) fp32 -> 256 images of 256x256
//   output : (256, 3969, 64) fp32; patch p: row0=4*(p/63), col0=4*(p%63)
// One block per (n, pr): stage the 8-row band (8 KB) into LDS coalesced,
// barrier, emit 63 patches (1008 float4) fully coalesced from LDS.

constexpr unsigned NPDIM   = 63;            // patch positions per dim
constexpr unsigned PATCHES = NPDIM * NPDIM; // 3969
constexpr unsigned CHUNKS  = 16;            // float4 chunks per 8x8 patch
constexpr unsigned ROWPAD  = 65;            // LDS row stride in float4s

using fv4 = __attribute__((ext_vector_type(4))) float;

__global__ __launch_bounds__(256) void image2patch_kernel(
    const fv4* __restrict__ in4, fv4* __restrict__ out4) {
    __shared__ fv4 lds4[8 * ROWPAD];        // 8.3 KB

    unsigned bid = blockIdx.x;
    unsigned n   = bid / NPDIM;             // image index, 0..255
    unsigned pr  = bid - n * NPDIM;         // patch row, 0..62

    // ---- stage 8-row band: rows 4*pr .. 4*pr+7, contiguous 2048 floats ----
    unsigned inbase4 = n * 16384u + pr * 256u;  // image=16384 f4, row=64 f4
    unsigned t = threadIdx.x;
    {
        unsigned r0 = t >> 6, c0 = t & 63u;
        lds4[r0 * ROWPAD + c0] = in4[inbase4 + t];
        unsigned i1 = t + 256u;
        unsigned r1 = i1 >> 6, c1 = i1 & 63u;
        lds4[r1 * ROWPAD + c1] = in4[inbase4 + i1];
    }
    __syncthreads();

    // ---- emit 63 patches = 1008 float4, coalesced, nontemporal ----
    unsigned outbase4 = (n * PATCHES + pr * NPDIM) * CHUNKS;
    #pragma unroll
    for (unsigned it = 0; it < 4; ++it) {
        unsigned i = it * 256u + t;
        if (i < NPDIM * CHUNKS) {                   // 1008
            unsigned pc  = i >> 4;                  // patch col, 0..62
            unsigned k4  = i & 15u;                 // chunk in patch
            unsigned di  = k4 >> 1;                 // row in patch, 0..7
            unsigned dj4 = k4 & 1u;                 // half-row, 0..1
            fv4 v = lds4[di * ROWPAD + pc + dj4];
            __builtin_nontemporal_store(v, &out4[outbase4 + i]);
        }
    }
}

extern "C" void kernel_launch(void* const* d_in, const int* in_sizes, int n_in,
                              void* d_out, int out_size, void* d_ws, size_t ws_size,
                              hipStream_t stream) {
    const fv4* in4 = (const fv4*)d_in[0];
    fv4* out4 = (fv4*)d_out;
    unsigned blocks = 256u * NPDIM;   // one block per (image, patch-row) = 16128
    image2patch_kernel<<<blocks, 256, 0, stream>>>(in4, out4);
}